// Round 4
// baseline (739.020 us; speedup 1.0000x reference)
//
#include <hip/hip_runtime.h>
#include <hip/hip_bf16.h>
#include <stdint.h>

using bf16 = __hip_bfloat16;

constexpr int B_ = 2;
constexpr int N_ = 2304;   // 48*48 post-conv nodes

// Workspace layout (float offsets). Total 1,634,368 floats = 6.24 MB.
constexpr int OFF_WC2   = 0;        // conv w  [tap][ic][oc] (9*64*64)
constexpr int OFF_WT2   = 36864;    // tconv w [tap][ic][oc]
constexpr int OFF_W1F   = 73728;    // [64][64]
constexpr int OFF_W2F   = 77824;
constexpr int OFF_WOUTF = 81920;    // [128][64]
constexpr int OFF_A1F   = 90112;    // 128
constexpr int OFF_A2F   = 90240;
constexpr int OFF_AOUTF = 90368;
constexpr int OFF_CBF   = 90496;    // 64
constexpr int OFF_TBF   = 90560;    // 64
constexpr int OFF_FLAG  = 90624;    // 1: inputs are fp32; 0: bf16
constexpr int OFF_SQ    = 90688;    // [B*N]; SQ + six s-arrays contiguous (zeroed by kc_x)
constexpr int OFF_S11   = 95296;
constexpr int OFF_S12   = 99904;
constexpr int OFF_S21   = 104512;
constexpr int OFF_S22   = 109120;
constexpr int OFF_S1O   = 113728;
constexpr int OFF_S2O   = 118336;
constexpr int OFF_KNN   = 122944;   // int [B*N][8] (7 used)
constexpr int OFF_BUF0  = 159808;   // 294912 floats each
constexpr int OFF_BUF1  = 454720;
constexpr int OFF_BUF2  = 749632;
constexpr int OFF_BUF3  = 1044544;
constexpr int OFF_XF32  = OFF_BUF1; // x as fp32, dead after k1_conv

__device__ __forceinline__ float bf2f_raw(unsigned short u) {
    return __uint_as_float(((unsigned int)u) << 16);
}

// ---------------------------------------------------------------------------
// KD: dtype probe (bf16 vs fp32 inputs) — kept for safety, ~3 µs.
// ---------------------------------------------------------------------------
__global__ __launch_bounds__(256) void kd_detect(const void* __restrict__ conv_w,
                                                 float* __restrict__ ws)
{
    __shared__ float red[256];
    const unsigned short* cw = (const unsigned short*)conv_w;
    int tid = threadIdx.x;
    float m = 0.f;
    for (int u = tid; u < 36864; u += 256) {
        float v = fabsf(bf2f_raw(cw[u]));
        if (v < 3.0e38f) m = fmaxf(m, v);
    }
    red[tid] = m;
    __syncthreads();
    for (int s = 128; s > 0; s >>= 1) {
        if (tid < s) red[tid] = fmaxf(red[tid], red[tid + s]);
        __syncthreads();
    }
    if (tid == 0) ws[OFF_FLAG] = (red[0] > 1.0e4f) ? 1.f : 0.f;
}

// ---------------------------------------------------------------------------
// KC: convert/transpose all small weights into fp32 ws slots (dual dtype).
// ---------------------------------------------------------------------------
__global__ __launch_bounds__(256) void kc_all(
    const void* conv_w, const void* conv_b, const void* W1, const void* a1,
    const void* W2, const void* a2, const void* Wout, const void* aout,
    const void* tconv_w, const void* tconv_b, float* __restrict__ ws)
{
    bool f32 = ws[OFF_FLAG] != 0.f;
    int idx = blockIdx.x * 256 + threadIdx.x;
    if (f32) {
        if (idx < 36864) {
            int tap = idx >> 12, ic = (idx >> 6) & 63, oc = idx & 63;
            ws[OFF_WC2 + idx] = ((const float*)conv_w)[(oc * 64 + ic) * 9 + tap];
            ws[OFF_WT2 + idx] = ((const float*)tconv_w)[(ic * 64 + oc) * 9 + tap];
        }
        if (idx < 4096) {
            ws[OFF_W1F + idx] = ((const float*)W1)[idx];
            ws[OFF_W2F + idx] = ((const float*)W2)[idx];
        }
        if (idx < 8192) ws[OFF_WOUTF + idx] = ((const float*)Wout)[idx];
        if (idx < 128) {
            ws[OFF_A1F + idx]   = ((const float*)a1)[idx];
            ws[OFF_A2F + idx]   = ((const float*)a2)[idx];
            ws[OFF_AOUTF + idx] = ((const float*)aout)[idx];
        }
        if (idx < 64) {
            ws[OFF_CBF + idx] = ((const float*)conv_b)[idx];
            ws[OFF_TBF + idx] = ((const float*)tconv_b)[idx];
        }
    } else {
        const unsigned short* cw = (const unsigned short*)conv_w;
        const unsigned short* tw = (const unsigned short*)tconv_w;
        if (idx < 36864) {
            int tap = idx >> 12, ic = (idx >> 6) & 63, oc = idx & 63;
            ws[OFF_WC2 + idx] = bf2f_raw(cw[(oc * 64 + ic) * 9 + tap]);
            ws[OFF_WT2 + idx] = bf2f_raw(tw[(ic * 64 + oc) * 9 + tap]);
        }
        if (idx < 4096) {
            ws[OFF_W1F + idx] = bf2f_raw(((const unsigned short*)W1)[idx]);
            ws[OFF_W2F + idx] = bf2f_raw(((const unsigned short*)W2)[idx]);
        }
        if (idx < 8192) ws[OFF_WOUTF + idx] = bf2f_raw(((const unsigned short*)Wout)[idx]);
        if (idx < 128) {
            ws[OFF_A1F + idx]   = bf2f_raw(((const unsigned short*)a1)[idx]);
            ws[OFF_A2F + idx]   = bf2f_raw(((const unsigned short*)a2)[idx]);
            ws[OFF_AOUTF + idx] = bf2f_raw(((const unsigned short*)aout)[idx]);
        }
        if (idx < 64) {
            ws[OFF_CBF + idx] = bf2f_raw(((const unsigned short*)conv_b)[idx]);
            ws[OFF_TBF + idx] = bf2f_raw(((const unsigned short*)tconv_b)[idx]);
        }
    }
}

// ---------------------------------------------------------------------------
// KX: x -> fp32 staging; also zero-init SQ + 6 s-arrays (atomic targets).
// grid 4608 x 256 over 1,179,648 elems.
// ---------------------------------------------------------------------------
__global__ __launch_bounds__(256) void kc_x(const void* __restrict__ x,
                                            float* __restrict__ ws)
{
    bool f32 = ws[OFF_FLAG] != 0.f;
    int i = blockIdx.x * 256 + threadIdx.x;
    float* xf = ws + OFF_XF32;
    if (f32) xf[i] = ((const float*)x)[i];
    else     xf[i] = bf2f_raw(((const unsigned short*)x)[i]);
    if (i < 32256) ws[OFF_SQ + i] = 0.f;   // SQ..S2O contiguous
}

// ---------------------------------------------------------------------------
// K1: 3x3 stride-2 conv pad 1 + fused sq (atomicAdd of per-group sum of f^2).
// grid (9, 8 oc-groups, B) x 256.
// ---------------------------------------------------------------------------
__global__ __launch_bounds__(256) void k1_conv(float* __restrict__ ws)
{
    int n   = blockIdx.x * 256 + threadIdx.x;   // 0..2303
    int ocb = blockIdx.y * 8;
    int b   = blockIdx.z;
    int oy = n / 48, ox = n - (n / 48) * 48;

    const float* xf = ws + OFF_XF32 + (size_t)b * 64 * 96 * 96;
    const float* wc2 = ws + OFF_WC2;
    float acc[8] = {0, 0, 0, 0, 0, 0, 0, 0};

    for (int ky = 0; ky < 3; ++ky) {
        int iy = 2 * oy - 1 + ky;
        bool vy = (unsigned)iy < 96u;
        int iyc = vy ? iy : 0;
        for (int kx = 0; kx < 3; ++kx) {
            int ix = 2 * ox - 1 + kx;
            bool v = vy && ((unsigned)ix < 96u);
            int ixc = v ? ix : 0;
            const float* xp = xf + iyc * 96 + ixc;
            const float* wb = wc2 + (ky * 3 + kx) * 4096 + ocb;
            #pragma unroll 8
            for (int ic = 0; ic < 64; ++ic) {
                float xv = xp[ic * 9216];
                xv = v ? xv : 0.f;
                const float* wr = wb + ic * 64;              // uniform -> s_load
                #pragma unroll
                for (int o = 0; o < 8; ++o) acc[o] += xv * wr[o];
            }
        }
    }
    float* featT = ws + OFF_BUF0 + (size_t)b * 64 * N_;
    const float* cb = ws + OFF_CBF;
    float ssum = 0.f;
    #pragma unroll
    for (int o = 0; o < 8; ++o) {
        float f = acc[o] + cb[ocb + o];
        featT[(ocb + o) * N_ + n] = f;
        ssum += f * f;
    }
    atomicAdd(ws + OFF_SQ + b * N_ + n, ssum);
}

// ---------------------------------------------------------------------------
// K2: exact top-7 per row. 4 rows per wave, 4 waves/block -> 16 rows/block.
// Rank key y_j = sq[j] - 2*dot(i,j)  (== d2 shifted by const sq[i]; same
// order, ties by index preserved; clamp only affects self which wins anyway).
// Row features via readfirstlane-forced scalar loads (s_load_dwordx4 serves
// 4 FMAs per coalesced fj load). Branch-free static-index top-7 insertion,
// final 7-pass lexicographic butterfly merge.
// grid 288 x 256
// ---------------------------------------------------------------------------
__global__ __launch_bounds__(256) void k2_knn(float* __restrict__ ws)
{
    int tid = threadIdx.x;
    int w = tid >> 6, lane = tid & 63;
    int b = blockIdx.x / 144;
    int i0raw = (blockIdx.x - b * 144) * 16 + w * 4;
    int i0 = __builtin_amdgcn_readfirstlane(i0raw);
    const float* fT = ws + OFF_BUF0 + (size_t)b * 64 * N_;
    const float* sq = ws + OFF_SQ + b * N_;

    float lv[4][7]; int lj[4][7];
    #pragma unroll
    for (int r = 0; r < 4; ++r)
        #pragma unroll
        for (int t = 0; t < 7; ++t) { lv[r][t] = 3.4e38f; lj[r][t] = 0x7fffffff; }

    for (int c0 = 0; c0 < 36; ++c0) {
        int j = c0 * 64 + lane;
        float a0 = 0.f, a1 = 0.f, a2 = 0.f, a3 = 0.f;
        #pragma unroll
        for (int c = 0; c < 64; ++c) {
            float fj = fT[c * N_ + j];              // coalesced
            const float* rp = fT + c * N_ + i0;     // uniform -> s_load_dwordx4
            a0 += fj * rp[0];
            a1 += fj * rp[1];
            a2 += fj * rp[2];
            a3 += fj * rp[3];
        }
        float sqj = sq[j];
        float y[4] = { sqj - 2.f * a0, sqj - 2.f * a1,
                       sqj - 2.f * a2, sqj - 2.f * a3 };
        #pragma unroll
        for (int r = 0; r < 4; ++r) {
            float yv = y[r];
            bool ins = (yv < lv[r][6]) || (yv == lv[r][6] && j < lj[r][6]);
            if (ins) {
                int pos = 0;
                #pragma unroll
                for (int t = 0; t < 7; ++t)
                    pos += ((lv[r][t] < yv) || (lv[r][t] == yv && lj[r][t] < j)) ? 1 : 0;
                #pragma unroll
                for (int p = 6; p > 0; --p) {
                    bool sh = (p > pos), eq = (p == pos);
                    float pv = lv[r][p - 1]; int pj = lj[r][p - 1];
                    lv[r][p] = eq ? yv : (sh ? pv : lv[r][p]);
                    lj[r][p] = eq ? j  : (sh ? pj : lj[r][p]);
                }
                if (pos == 0) { lv[r][0] = yv; lj[r][0] = j; }
            }
        }
    }

    int* knn = (int*)(ws + OFF_KNN);
    #pragma unroll
    for (int r = 0; r < 4; ++r) {
        int myj = 0;
        for (int pass = 0; pass < 7; ++pass) {
            // lane-local lexicographic min over remaining entries
            float bv = lv[r][0]; int bj = lj[r][0];
            #pragma unroll
            for (int t = 1; t < 7; ++t)
                if (lv[r][t] < bv || (lv[r][t] == bv && lj[r][t] < bj)) {
                    bv = lv[r][t]; bj = lj[r][t];
                }
            #pragma unroll
            for (int off = 1; off < 64; off <<= 1) {
                float ov = __shfl_xor(bv, off);
                int   oj = __shfl_xor(bj, off);
                if (ov < bv || (ov == bv && oj < bj)) { bv = ov; bj = oj; }
            }
            // consume (j unique across lanes)
            #pragma unroll
            for (int t = 0; t < 7; ++t)
                if (lj[r][t] == bj) { lv[r][t] = 3.4e38f; lj[r][t] = 0x7fffffff; }
            if (lane == pass) myj = bj;
        }
        if (lane < 7)
            knn[(size_t)(b * N_ + i0 + r) * 8 + lane] = myj;
    }
}

// ---------------------------------------------------------------------------
// K_lin: both GAT input projections in one launch.
// grid (18 n-chunks, 8 oc-groups, 2 layers) x 256; s1/s2 partials via atomics.
// ---------------------------------------------------------------------------
__global__ __launch_bounds__(256) void k_lin(float* __restrict__ ws)
{
    int layer = blockIdx.z;
    const float* W  = ws + (layer ? OFF_W2F : OFF_W1F);
    const float* a  = ws + (layer ? OFF_A2F : OFF_A1F);
    float* outT = ws + (layer ? OFF_BUF3 : OFF_BUF1);
    float* s1   = ws + (layer ? OFF_S21 : OFF_S11);
    float* s2   = ws + (layer ? OFF_S22 : OFF_S12);
    int ocb = blockIdx.y * 8;
    int i = blockIdx.x * 256 + threadIdx.x;
    int b = i / N_, n = i - b * N_;
    const float* in_b = ws + OFF_BUF0 + (size_t)b * 64 * N_;

    float acc[8] = {0, 0, 0, 0, 0, 0, 0, 0};
    #pragma unroll 8
    for (int k = 0; k < 64; ++k) {
        float xv = in_b[k * N_ + n];
        const float* wr = W + k * 64 + ocb;        // uniform -> s_load
        #pragma unroll
        for (int o = 0; o < 8; ++o) acc[o] += xv * wr[o];
    }
    float* ob = outT + (size_t)b * 64 * N_;
    float p1 = 0.f, p2 = 0.f;
    #pragma unroll
    for (int o = 0; o < 8; ++o) {
        ob[(ocb + o) * N_ + n] = acc[o];
        p1 += acc[o] * a[ocb + o];
        p2 += acc[o] * a[64 + ocb + o];
    }
    atomicAdd(s1 + i, p1);
    atomicAdd(s2 + i, p2);
}

// ---------------------------------------------------------------------------
// K_lin2: Whout = [h1|h2] @ Wout.  h1=BUF2, h2=BUF0, out=BUF1.
// grid (18, 8) x 256.
// ---------------------------------------------------------------------------
__global__ __launch_bounds__(256) void k_lin2(float* __restrict__ ws)
{
    int ocb = blockIdx.y * 8;
    int i = blockIdx.x * 256 + threadIdx.x;
    int b = i / N_, n = i - b * N_;
    const float* h1 = ws + OFF_BUF2 + (size_t)b * 64 * N_;
    const float* h2 = ws + OFF_BUF0 + (size_t)b * 64 * N_;
    const float* W  = ws + OFF_WOUTF;
    const float* a  = ws + OFF_AOUTF;

    float acc[8] = {0, 0, 0, 0, 0, 0, 0, 0};
    #pragma unroll 8
    for (int k = 0; k < 64; ++k) {
        float xv = h1[k * N_ + n];
        const float* wr = W + k * 64 + ocb;
        #pragma unroll
        for (int o = 0; o < 8; ++o) acc[o] += xv * wr[o];
    }
    #pragma unroll 8
    for (int k = 0; k < 64; ++k) {
        float xv = h2[k * N_ + n];
        const float* wr = W + (64 + k) * 64 + ocb;
        #pragma unroll
        for (int o = 0; o < 8; ++o) acc[o] += xv * wr[o];
    }
    float* ob = ws + OFF_BUF1 + (size_t)b * 64 * N_;
    float p1 = 0.f, p2 = 0.f;
    #pragma unroll
    for (int o = 0; o < 8; ++o) {
        ob[(ocb + o) * N_ + n] = acc[o];
        p1 += acc[o] * a[ocb + o];
        p2 += acc[o] * a[64 + ocb + o];
    }
    atomicAdd(ws + OFF_S1O + i, p1);
    atomicAdd(ws + OFF_S2O + i, p2);
}

// ---------------------------------------------------------------------------
// K_attn12: GAT sparse softmax+aggregate+ELU for layers 1 & 2 in one launch.
// grid (18 n-chunks, 8 c-groups, 2 layers) x 256.
// layer1: Wh=BUF1 -> h1=BUF2;  layer2: Wh=BUF3 -> h2=BUF0.
// ---------------------------------------------------------------------------
__device__ __forceinline__ void attn_body(
    const float* __restrict__ WhT, const float* __restrict__ s1,
    const float* __restrict__ s2, const int* __restrict__ knn,
    float* __restrict__ out, int i, int b, int n, int ccb)
{
    const int* kp = knn + (size_t)i * 8;
    int j[7];
    #pragma unroll
    for (int t = 0; t < 7; ++t) {
        int jt = kp[t];
        j[t] = ((unsigned)jt < (unsigned)N_) ? jt : 0;
    }
    float si = s1[i];
    const float* s2b = s2 + b * N_;
    float e[7];
    #pragma unroll
    for (int t = 0; t < 7; ++t) {
        float v = si + s2b[j[t]];
        e[t] = v > 0.f ? v : 0.2f * v;     // leaky_relu 0.2
    }
    float m = e[0];
    #pragma unroll
    for (int t = 1; t < 7; ++t) m = fmaxf(m, e[t]);
    float ssum = 0.f;
    #pragma unroll
    for (int t = 0; t < 7; ++t) { e[t] = __expf(e[t] - m); ssum += e[t]; }
    float inv = 1.f / ssum;
    #pragma unroll
    for (int t = 0; t < 7; ++t) e[t] *= inv;

    const float* Wb = WhT + (size_t)b * 64 * N_;
    float* ob = out + (size_t)b * 64 * N_;
    #pragma unroll
    for (int c = ccb; c < ccb + 8; ++c) {
        const float* Wc = Wb + c * N_;
        float acc = 0.f;
        #pragma unroll
        for (int t = 0; t < 7; ++t) acc += e[t] * Wc[j[t]];
        acc = acc > 0.f ? acc : expm1f(acc);   // ELU
        ob[c * N_ + n] = acc;
    }
}

__global__ __launch_bounds__(256) void k_attn12(float* __restrict__ ws)
{
    int layer = blockIdx.z;
    const float* WhT = ws + (layer ? OFF_BUF3 : OFF_BUF1);
    const float* s1  = ws + (layer ? OFF_S21 : OFF_S11);
    const float* s2  = ws + (layer ? OFF_S22 : OFF_S12);
    float* out       = ws + (layer ? OFF_BUF0 : OFF_BUF2);
    int ccb = blockIdx.y * 8;
    int i = blockIdx.x * 256 + threadIdx.x;
    int b = i / N_, n = i - b * N_;
    attn_body(WhT, s1, s2, (const int*)(ws + OFF_KNN), out, i, b, n, ccb);
}

// K_attn_out: output GAT layer.  Wh=BUF1 -> g=BUF3.  grid (18, 8) x 256.
__global__ __launch_bounds__(256) void k_attn_out(float* __restrict__ ws)
{
    int ccb = blockIdx.y * 8;
    int i = blockIdx.x * 256 + threadIdx.x;
    int b = i / N_, n = i - b * N_;
    attn_body(ws + OFF_BUF1, ws + OFF_S1O, ws + OFF_S2O,
              (const int*)(ws + OFF_KNN), ws + OFF_BUF3, i, b, n, ccb);
}

// ---------------------------------------------------------------------------
// K7: ConvTranspose2d k=3 s=2 p=1 op=1 : 48x48 -> 96x96, reads g=BUF3.
// grid (36 pix-chunks, 8 oc-groups, B) x 256; dual-dtype output store.
// ---------------------------------------------------------------------------
__global__ __launch_bounds__(256) void k7_tconv(float* __restrict__ ws,
                                                void* __restrict__ outp)
{
    bool f32 = ws[OFF_FLAG] != 0.f;
    int pix = blockIdx.x * 256 + threadIdx.x;   // 0..9215
    int ocb = blockIdx.y * 8;
    int b   = blockIdx.z;
    int oy = pix / 96, ox = pix - (pix / 96) * 96;

    const float* gT  = ws + OFF_BUF3 + (size_t)b * 64 * N_;
    const float* wt2 = ws + OFF_WT2;
    float acc[8] = {0, 0, 0, 0, 0, 0, 0, 0};

    for (int ky = 0; ky < 3; ++ky) {
        int ty = oy + 1 - ky;
        bool vy = ((ty & 1) == 0) && ((unsigned)(ty >> 1) < 48u);
        int iy = vy ? (ty >> 1) : 0;
        for (int kx = 0; kx < 3; ++kx) {
            int tx = ox + 1 - kx;
            bool v = vy && ((tx & 1) == 0) && ((unsigned)(tx >> 1) < 48u);
            int ix = v ? (tx >> 1) : 0;
            const float* gp = gT + iy * 48 + ix;
            const float* wb = wt2 + (ky * 3 + kx) * 4096 + ocb;
            #pragma unroll 8
            for (int ic = 0; ic < 64; ++ic) {
                float gv = gp[ic * N_];
                gv = v ? gv : 0.f;
                const float* wr = wb + ic * 64;    // uniform -> s_load
                #pragma unroll
                for (int o = 0; o < 8; ++o) acc[o] += gv * wr[o];
            }
        }
    }
    const float* tb = ws + OFF_TBF;
    size_t base = ((size_t)(b * 64 + ocb) * 96 + oy) * 96 + ox;
    if (f32) {
        float* op = (float*)outp;
        #pragma unroll
        for (int o = 0; o < 8; ++o) op[base + (size_t)o * 9216] = acc[o] + tb[ocb + o];
    } else {
        bf16* op = (bf16*)outp;
        #pragma unroll
        for (int o = 0; o < 8; ++o)
            op[base + (size_t)o * 9216] = __float2bfloat16(acc[o] + tb[ocb + o]);
    }
}

// ---------------------------------------------------------------------------
extern "C" void kernel_launch(void* const* d_in, const int* in_sizes, int n_in,
                              void* d_out, int out_size, void* d_ws, size_t ws_size,
                              hipStream_t stream)
{
    float* ws = (float*)d_ws;

    hipLaunchKernelGGL(kd_detect, dim3(1), dim3(256), 0, stream, d_in[1], ws);
    hipLaunchKernelGGL(kc_all, dim3(144), dim3(256), 0, stream,
                       d_in[1], d_in[2], d_in[3], d_in[4], d_in[5], d_in[6],
                       d_in[7], d_in[8], d_in[9], d_in[10], ws);
    hipLaunchKernelGGL(kc_x, dim3(4608), dim3(256), 0, stream, d_in[0], ws);
    hipLaunchKernelGGL(k1_conv, dim3(9, 8, 2), dim3(256), 0, stream, ws);
    hipLaunchKernelGGL(k2_knn, dim3(288), dim3(256), 0, stream, ws);
    hipLaunchKernelGGL(k_lin, dim3(18, 8, 2), dim3(256), 0, stream, ws);
    hipLaunchKernelGGL(k_attn12, dim3(18, 8, 2), dim3(256), 0, stream, ws);
    hipLaunchKernelGGL(k_lin2, dim3(18, 8), dim3(256), 0, stream, ws);
    hipLaunchKernelGGL(k_attn_out, dim3(18, 8), dim3(256), 0, stream, ws);
    hipLaunchKernelGGL(k7_tconv, dim3(36, 8, 2), dim3(256), 0, stream, ws, d_out);
}

// Round 5
// 468.281 us; speedup vs baseline: 1.5782x; 1.5782x over previous
//
#include <hip/hip_runtime.h>
#include <hip/hip_bf16.h>
#include <stdint.h>

using bf16 = __hip_bfloat16;

constexpr int B_ = 2;
constexpr int N_ = 2304;   // 48*48 post-conv nodes

// Workspace layout (float offsets). Max used = 5.36 MB (same as R3/R4 which passed).
constexpr int OFF_WC2   = 0;        // conv w  [tap][ic][oc] (9*64*64)
constexpr int OFF_WT2   = 36864;    // tconv w [tap][ic][oc]
constexpr int OFF_W1F   = 73728;    // [64][64]
constexpr int OFF_W2F   = 77824;
constexpr int OFF_WOUTF = 81920;    // [128][64]
constexpr int OFF_A1F   = 90112;    // 128
constexpr int OFF_A2F   = 90240;
constexpr int OFF_AOUTF = 90368;
constexpr int OFF_CBF   = 90496;    // 64
constexpr int OFF_TBF   = 90560;    // 64
constexpr int OFF_SQ    = 90688;    // [B*N]; SQ + six s-arrays contiguous (zeroed by kc)
constexpr int OFF_S11   = 95296;
constexpr int OFF_S12   = 99904;
constexpr int OFF_S21   = 104512;
constexpr int OFF_S22   = 109120;
constexpr int OFF_S1O   = 113728;
constexpr int OFF_S2O   = 118336;
constexpr int OFF_KNN   = 122944;   // int [B*N][8] (7 used)
constexpr int OFF_BUF0  = 159808;   // 294912 floats each
constexpr int OFF_BUF1  = 454720;
constexpr int OFF_BUF2  = 749632;
constexpr int OFF_BUF3  = 1044544;
constexpr int OFF_XF32  = OFF_BUF1; // x as fp32, dead after k1_conv
constexpr int OFF_PY    = OFF_BUF1;           // partial top-7 y  [B*N][2][8]
constexpr int OFF_PJ    = OFF_BUF1 + 73728;   // partial top-7 j  [B*N][2][8]

__device__ __forceinline__ float bf2f_raw(unsigned short u) {
    return __uint_as_float(((unsigned int)u) << 16);
}

// Per-block dtype probe: 64 low-halves of conv_w. fp32 misread -> ~45% of
// halves decode to |bf16|>1e4; true bf16 (sigma=.05) never does.
// P(misdetect) ~ 0.55^64 ~ 2e-17.
__device__ __forceinline__ bool detect_f32(const void* conv_w) {
    const unsigned short* cw = (const unsigned short*)conv_w;
    float m = 0.f;
    #pragma unroll
    for (int u = 0; u < 64; ++u) {
        float v = fabsf(bf2f_raw(cw[u]));
        if (v < 3.0e38f) m = fmaxf(m, v);   // skip inf/NaN bit patterns
    }
    return m > 1.0e4f;
}

// ---------------------------------------------------------------------------
// KC: merged prep. grid 4608 x 256 (i = global elem over x).
//  - all blocks: x -> fp32 staging at XF32; zero SQ..S2O
//  - blocks with idx<36864: weight convert/transpose
// ---------------------------------------------------------------------------
__global__ __launch_bounds__(256) void kc_prep(
    const void* __restrict__ x,
    const void* conv_w, const void* conv_b, const void* W1, const void* a1,
    const void* W2, const void* a2, const void* Wout, const void* aout,
    const void* tconv_w, const void* tconv_b, float* __restrict__ ws)
{
    bool f32 = detect_f32(conv_w);
    int i = blockIdx.x * 256 + threadIdx.x;   // < 1,179,648 exactly
    float* xf = ws + OFF_XF32;
    if (f32) xf[i] = ((const float*)x)[i];
    else     xf[i] = bf2f_raw(((const unsigned short*)x)[i]);
    if (i < 32256) ws[OFF_SQ + i] = 0.f;      // SQ..S2O contiguous zero-init

    int idx = i;
    if (idx < 36864) {
        int tap = idx >> 12, ic = (idx >> 6) & 63, oc = idx & 63;
        if (f32) {
            ws[OFF_WC2 + idx] = ((const float*)conv_w)[(oc * 64 + ic) * 9 + tap];
            ws[OFF_WT2 + idx] = ((const float*)tconv_w)[(ic * 64 + oc) * 9 + tap];
        } else {
            ws[OFF_WC2 + idx] = bf2f_raw(((const unsigned short*)conv_w)[(oc * 64 + ic) * 9 + tap]);
            ws[OFF_WT2 + idx] = bf2f_raw(((const unsigned short*)tconv_w)[(ic * 64 + oc) * 9 + tap]);
        }
        if (idx < 4096) {
            if (f32) {
                ws[OFF_W1F + idx] = ((const float*)W1)[idx];
                ws[OFF_W2F + idx] = ((const float*)W2)[idx];
            } else {
                ws[OFF_W1F + idx] = bf2f_raw(((const unsigned short*)W1)[idx]);
                ws[OFF_W2F + idx] = bf2f_raw(((const unsigned short*)W2)[idx]);
            }
        }
        if (idx < 8192)
            ws[OFF_WOUTF + idx] = f32 ? ((const float*)Wout)[idx]
                                      : bf2f_raw(((const unsigned short*)Wout)[idx]);
        if (idx < 128) {
            if (f32) {
                ws[OFF_A1F + idx]   = ((const float*)a1)[idx];
                ws[OFF_A2F + idx]   = ((const float*)a2)[idx];
                ws[OFF_AOUTF + idx] = ((const float*)aout)[idx];
            } else {
                ws[OFF_A1F + idx]   = bf2f_raw(((const unsigned short*)a1)[idx]);
                ws[OFF_A2F + idx]   = bf2f_raw(((const unsigned short*)a2)[idx]);
                ws[OFF_AOUTF + idx] = bf2f_raw(((const unsigned short*)aout)[idx]);
            }
        }
        if (idx < 64) {
            if (f32) {
                ws[OFF_CBF + idx] = ((const float*)conv_b)[idx];
                ws[OFF_TBF + idx] = ((const float*)tconv_b)[idx];
            } else {
                ws[OFF_CBF + idx] = bf2f_raw(((const unsigned short*)conv_b)[idx]);
                ws[OFF_TBF + idx] = bf2f_raw(((const unsigned short*)tconv_b)[idx]);
            }
        }
    }
}

// ---------------------------------------------------------------------------
// K1: 3x3 stride-2 conv pad 1 + fused sq (atomicAdd of per-group sum of f^2).
// grid (9, 8 oc-groups, B) x 256.
// ---------------------------------------------------------------------------
__global__ __launch_bounds__(256) void k1_conv(float* __restrict__ ws)
{
    int n   = blockIdx.x * 256 + threadIdx.x;   // 0..2303
    int ocb = blockIdx.y * 8;
    int b   = blockIdx.z;
    int oy = n / 48, ox = n - (n / 48) * 48;

    const float* xf = ws + OFF_XF32 + (size_t)b * 64 * 96 * 96;
    const float* wc2 = ws + OFF_WC2;
    float acc[8] = {0, 0, 0, 0, 0, 0, 0, 0};

    for (int ky = 0; ky < 3; ++ky) {
        int iy = 2 * oy - 1 + ky;
        bool vy = (unsigned)iy < 96u;
        int iyc = vy ? iy : 0;
        for (int kx = 0; kx < 3; ++kx) {
            int ix = 2 * ox - 1 + kx;
            bool v = vy && ((unsigned)ix < 96u);
            int ixc = v ? ix : 0;
            const float* xp = xf + iyc * 96 + ixc;
            const float* wb = wc2 + (ky * 3 + kx) * 4096 + ocb;
            #pragma unroll 8
            for (int ic = 0; ic < 64; ++ic) {
                float xv = xp[ic * 9216];
                xv = v ? xv : 0.f;
                const float* wr = wb + ic * 64;
                #pragma unroll
                for (int o = 0; o < 8; ++o) acc[o] += xv * wr[o];
            }
        }
    }
    float* featT = ws + OFF_BUF0 + (size_t)b * 64 * N_;
    const float* cb = ws + OFF_CBF;
    float ssum = 0.f;
    #pragma unroll
    for (int o = 0; o < 8; ++o) {
        float f = acc[o] + cb[ocb + o];
        featT[(ocb + o) * N_ + n] = f;
        ssum += f * f;
    }
    atomicAdd(ws + OFF_SQ + b * N_ + n, ssum);
}

// ---------------------------------------------------------------------------
// TR: featT [b][c][n] -> feat_nc [row][c] (row = b*N+n), for k2's float4 loads.
// grid 288 x 256: thread = (rowgroup of 16) x (c4 of 16).
// ---------------------------------------------------------------------------
__global__ __launch_bounds__(256) void tr_nc(float* __restrict__ ws)
{
    int tid = threadIdx.x;
    int i = blockIdx.x * 16 + (tid & 15);     // global row
    int c4 = tid >> 4;                        // 0..15
    int b = i / N_, n = i - b * N_;
    const float* fT = ws + OFF_BUF0 + (size_t)b * 64 * N_ + n;
    float4 v;
    v.x = fT[(c4 * 4 + 0) * N_];
    v.y = fT[(c4 * 4 + 1) * N_];
    v.z = fT[(c4 * 4 + 2) * N_];
    v.w = fT[(c4 * 4 + 3) * N_];
    *((float4*)(ws + OFF_BUF2 + (size_t)i * 64 + c4 * 4)) = v;
}

// ---------------------------------------------------------------------------
// K2: top-7 per row over half the columns. Block = 4 waves = 16 rows staged
// in LDS; wave owns 4 rows; lane sweeps 18 j (j = jh*1152 + t*64 + lane).
// Per j: 16 float4 chunks -> 16 indep FMA chains into 4 row-accs.
// Rank key y = sq[j] - 2*dot (order == d2, stable ties by j).
// Per-lane sorted top-7 insert, then 7-pass (y,j)-butterfly merge -> PART.
// grid (288 rowgroups, 2 halves) x 256.
// ---------------------------------------------------------------------------
__global__ __launch_bounds__(256) void k2_knn(float* __restrict__ ws)
{
    __shared__ float fi[16][64];
    int tid = threadIdx.x;
    int i0  = blockIdx.x * 16;        // global row base (16 | N_, no straddle)
    int jh  = blockIdx.y;
    int b   = i0 / N_;
    const float* fnc = ws + OFF_BUF2;
    const float* sq  = ws + OFF_SQ + b * N_;

    {   // stage 16 rows x 64 c (coalesced read, 2-way-free LDS write)
        int r = tid >> 4, c4 = tid & 15;
        float4 v = *((const float4*)(fnc + (size_t)(i0 + r) * 64 + c4 * 4));
        *((float4*)&fi[r][c4 * 4]) = v;
    }
    __syncthreads();

    int w = tid >> 6, lane = tid & 63;
    int r0 = w * 4;

    float lv[4][7]; int lj[4][7];
    #pragma unroll
    for (int r = 0; r < 4; ++r)
        #pragma unroll
        for (int t = 0; t < 7; ++t) { lv[r][t] = 3.4e38f; lj[r][t] = 0x7fffffff; }

    int jbase = jh * 1152;
    for (int t = 0; t < 18; ++t) {
        int j = jbase + t * 64 + lane;
        const float4* fj4 = (const float4*)(fnc + (size_t)(b * N_ + j) * 64);
        float4 a0 = {0,0,0,0}, a1 = {0,0,0,0}, a2 = {0,0,0,0}, a3 = {0,0,0,0};
        #pragma unroll
        for (int c4 = 0; c4 < 16; ++c4) {
            float4 fj = fj4[c4];
            float4 f0 = *((const float4*)&fi[r0 + 0][c4 * 4]);
            float4 f1 = *((const float4*)&fi[r0 + 1][c4 * 4]);
            float4 f2 = *((const float4*)&fi[r0 + 2][c4 * 4]);
            float4 f3 = *((const float4*)&fi[r0 + 3][c4 * 4]);
            a0.x += fj.x * f0.x; a0.y += fj.y * f0.y; a0.z += fj.z * f0.z; a0.w += fj.w * f0.w;
            a1.x += fj.x * f1.x; a1.y += fj.y * f1.y; a1.z += fj.z * f1.z; a1.w += fj.w * f1.w;
            a2.x += fj.x * f2.x; a2.y += fj.y * f2.y; a2.z += fj.z * f2.z; a2.w += fj.w * f2.w;
            a3.x += fj.x * f3.x; a3.y += fj.y * f3.y; a3.z += fj.z * f3.z; a3.w += fj.w * f3.w;
        }
        float sqj = sq[j];
        float y[4];
        y[0] = sqj - 2.f * ((a0.x + a0.y) + (a0.z + a0.w));
        y[1] = sqj - 2.f * ((a1.x + a1.y) + (a1.z + a1.w));
        y[2] = sqj - 2.f * ((a2.x + a2.y) + (a2.z + a2.w));
        y[3] = sqj - 2.f * ((a3.x + a3.y) + (a3.z + a3.w));
        #pragma unroll
        for (int r = 0; r < 4; ++r) {
            float yv = y[r];
            bool ins = (yv < lv[r][6]) || (yv == lv[r][6] && j < lj[r][6]);
            if (ins) {
                int pos = 0;
                #pragma unroll
                for (int q = 0; q < 7; ++q)
                    pos += ((lv[r][q] < yv) || (lv[r][q] == yv && lj[r][q] < j)) ? 1 : 0;
                #pragma unroll
                for (int p = 6; p > 0; --p) {
                    bool sh = (p > pos), eq = (p == pos);
                    float pv = lv[r][p - 1]; int pj2 = lj[r][p - 1];
                    lv[r][p] = eq ? yv : (sh ? pv : lv[r][p]);
                    lj[r][p] = eq ? j  : (sh ? pj2 : lj[r][p]);
                }
                if (pos == 0) { lv[r][0] = yv; lj[r][0] = j; }
            }
        }
    }

    // wave-level 7-smallest merge per row (lists sorted; j unique per lane-set)
    float* py = ws + OFF_PY;
    int*   pj = (int*)(ws + OFF_PJ);
    #pragma unroll
    for (int r = 0; r < 4; ++r) {
        int ptr = 0, myj = 0; float myv = 0.f;
        for (int pass = 0; pass < 7; ++pass) {
            float bv = (ptr < 7) ? lv[r][ptr] : 3.4e38f;
            int   bj = (ptr < 7) ? lj[r][ptr] : 0x7fffffff;
            #pragma unroll
            for (int off = 1; off < 64; off <<= 1) {
                float ov = __shfl_xor(bv, off);
                int   oj = __shfl_xor(bj, off);
                if (ov < bv || (ov == bv && oj < bj)) { bv = ov; bj = oj; }
            }
            if (ptr < 7 && lj[r][ptr] == bj) ++ptr;   // owning lane advances
            if (lane == pass) { myv = bv; myj = bj; }
        }
        if (lane < 7) {
            size_t base = ((size_t)(i0 + r0 + r) * 2 + jh) * 8 + lane;
            py[base] = myv;
            pj[base] = myj;
        }
    }
}

// ---------------------------------------------------------------------------
// K2M: merge the two sorted partial 7-lists per row -> KNN.  grid 18 x 256.
// ---------------------------------------------------------------------------
__global__ __launch_bounds__(256) void k2_merge(float* __restrict__ ws)
{
    int row = blockIdx.x * 256 + threadIdx.x;   // < 4608
    const float* py = ws + OFF_PY + (size_t)row * 16;
    const int*   pj = (const int*)(ws + OFF_PJ) + (size_t)row * 16;
    int* kout = (int*)(ws + OFF_KNN) + (size_t)row * 8;
    int p0 = 0, p1 = 8;
    #pragma unroll
    for (int t = 0; t < 7; ++t) {
        float y0 = py[p0], y1 = py[p1];
        int   j0 = pj[p0], j1 = pj[p1];
        bool take0 = (y0 < y1) || (y0 == y1 && j0 < j1);
        kout[t] = take0 ? j0 : j1;
        p0 += take0 ? 1 : 0;
        p1 += take0 ? 0 : 1;
    }
}

// ---------------------------------------------------------------------------
// K_lin: both GAT input projections.  grid (18, 8 oc, 2 layers) x 256.
// ---------------------------------------------------------------------------
__global__ __launch_bounds__(256) void k_lin(float* __restrict__ ws)
{
    int layer = blockIdx.z;
    const float* W  = ws + (layer ? OFF_W2F : OFF_W1F);
    const float* a  = ws + (layer ? OFF_A2F : OFF_A1F);
    float* outT = ws + (layer ? OFF_BUF3 : OFF_BUF1);
    float* s1   = ws + (layer ? OFF_S21 : OFF_S11);
    float* s2   = ws + (layer ? OFF_S22 : OFF_S12);
    int ocb = blockIdx.y * 8;
    int i = blockIdx.x * 256 + threadIdx.x;
    int b = i / N_, n = i - b * N_;
    const float* in_b = ws + OFF_BUF0 + (size_t)b * 64 * N_;

    float acc[8] = {0, 0, 0, 0, 0, 0, 0, 0};
    #pragma unroll 8
    for (int k = 0; k < 64; ++k) {
        float xv = in_b[k * N_ + n];
        const float* wr = W + k * 64 + ocb;
        #pragma unroll
        for (int o = 0; o < 8; ++o) acc[o] += xv * wr[o];
    }
    float* ob = outT + (size_t)b * 64 * N_;
    float p1 = 0.f, p2 = 0.f;
    #pragma unroll
    for (int o = 0; o < 8; ++o) {
        ob[(ocb + o) * N_ + n] = acc[o];
        p1 += acc[o] * a[ocb + o];
        p2 += acc[o] * a[64 + ocb + o];
    }
    atomicAdd(s1 + i, p1);
    atomicAdd(s2 + i, p2);
}

// ---------------------------------------------------------------------------
// K_lin2: Whout = [h1|h2] @ Wout.  h1=BUF2, h2=BUF0, out=BUF1.  grid (18,8).
// ---------------------------------------------------------------------------
__global__ __launch_bounds__(256) void k_lin2(float* __restrict__ ws)
{
    int ocb = blockIdx.y * 8;
    int i = blockIdx.x * 256 + threadIdx.x;
    int b = i / N_, n = i - b * N_;
    const float* h1 = ws + OFF_BUF2 + (size_t)b * 64 * N_;
    const float* h2 = ws + OFF_BUF0 + (size_t)b * 64 * N_;
    const float* W  = ws + OFF_WOUTF;
    const float* a  = ws + OFF_AOUTF;

    float acc[8] = {0, 0, 0, 0, 0, 0, 0, 0};
    #pragma unroll 8
    for (int k = 0; k < 64; ++k) {
        float xv = h1[k * N_ + n];
        const float* wr = W + k * 64 + ocb;
        #pragma unroll
        for (int o = 0; o < 8; ++o) acc[o] += xv * wr[o];
    }
    #pragma unroll 8
    for (int k = 0; k < 64; ++k) {
        float xv = h2[k * N_ + n];
        const float* wr = W + (64 + k) * 64 + ocb;
        #pragma unroll
        for (int o = 0; o < 8; ++o) acc[o] += xv * wr[o];
    }
    float* ob = ws + OFF_BUF1 + (size_t)b * 64 * N_;
    float p1 = 0.f, p2 = 0.f;
    #pragma unroll
    for (int o = 0; o < 8; ++o) {
        ob[(ocb + o) * N_ + n] = acc[o];
        p1 += acc[o] * a[ocb + o];
        p2 += acc[o] * a[64 + ocb + o];
    }
    atomicAdd(ws + OFF_S1O + i, p1);
    atomicAdd(ws + OFF_S2O + i, p2);
}

// ---------------------------------------------------------------------------
// K_attn*: sparse GAT softmax over 7-NN + ELU.
// ---------------------------------------------------------------------------
__device__ __forceinline__ void attn_body(
    const float* __restrict__ WhT, const float* __restrict__ s1,
    const float* __restrict__ s2, const int* __restrict__ knn,
    float* __restrict__ out, int i, int b, int n, int ccb)
{
    const int* kp = knn + (size_t)i * 8;
    int j[7];
    #pragma unroll
    for (int t = 0; t < 7; ++t) {
        int jt = kp[t];
        j[t] = ((unsigned)jt < (unsigned)N_) ? jt : 0;
    }
    float si = s1[i];
    const float* s2b = s2 + b * N_;
    float e[7];
    #pragma unroll
    for (int t = 0; t < 7; ++t) {
        float v = si + s2b[j[t]];
        e[t] = v > 0.f ? v : 0.2f * v;     // leaky_relu 0.2
    }
    float m = e[0];
    #pragma unroll
    for (int t = 1; t < 7; ++t) m = fmaxf(m, e[t]);
    float ssum = 0.f;
    #pragma unroll
    for (int t = 0; t < 7; ++t) { e[t] = __expf(e[t] - m); ssum += e[t]; }
    float inv = 1.f / ssum;
    #pragma unroll
    for (int t = 0; t < 7; ++t) e[t] *= inv;

    const float* Wb = WhT + (size_t)b * 64 * N_;
    float* ob = out + (size_t)b * 64 * N_;
    #pragma unroll
    for (int c = ccb; c < ccb + 8; ++c) {
        const float* Wc = Wb + c * N_;
        float acc = 0.f;
        #pragma unroll
        for (int t = 0; t < 7; ++t) acc += e[t] * Wc[j[t]];
        acc = acc > 0.f ? acc : expm1f(acc);   // ELU
        ob[c * N_ + n] = acc;
    }
}

__global__ __launch_bounds__(256) void k_attn12(float* __restrict__ ws)
{
    int layer = blockIdx.z;
    const float* WhT = ws + (layer ? OFF_BUF3 : OFF_BUF1);
    const float* s1  = ws + (layer ? OFF_S21 : OFF_S11);
    const float* s2  = ws + (layer ? OFF_S22 : OFF_S12);
    float* out       = ws + (layer ? OFF_BUF0 : OFF_BUF2);
    int ccb = blockIdx.y * 8;
    int i = blockIdx.x * 256 + threadIdx.x;
    int b = i / N_, n = i - b * N_;
    attn_body(WhT, s1, s2, (const int*)(ws + OFF_KNN), out, i, b, n, ccb);
}

__global__ __launch_bounds__(256) void k_attn_out(float* __restrict__ ws)
{
    int ccb = blockIdx.y * 8;
    int i = blockIdx.x * 256 + threadIdx.x;
    int b = i / N_, n = i - b * N_;
    attn_body(ws + OFF_BUF1, ws + OFF_S1O, ws + OFF_S2O,
              (const int*)(ws + OFF_KNN), ws + OFF_BUF3, i, b, n, ccb);
}

// ---------------------------------------------------------------------------
// K7: ConvTranspose2d k=3 s=2 p=1 op=1 : 48x48 -> 96x96, reads g=BUF3.
// grid (36, 8 oc, B) x 256; dual-dtype output store.
// ---------------------------------------------------------------------------
__global__ __launch_bounds__(256) void k7_tconv(float* __restrict__ ws,
                                                const void* __restrict__ conv_w,
                                                void* __restrict__ outp)
{
    bool f32 = detect_f32(conv_w);
    int pix = blockIdx.x * 256 + threadIdx.x;   // 0..9215
    int ocb = blockIdx.y * 8;
    int b   = blockIdx.z;
    int oy = pix / 96, ox = pix - (pix / 96) * 96;

    const float* gT  = ws + OFF_BUF3 + (size_t)b * 64 * N_;
    const float* wt2 = ws + OFF_WT2;
    float acc[8] = {0, 0, 0, 0, 0, 0, 0, 0};

    for (int ky = 0; ky < 3; ++ky) {
        int ty = oy + 1 - ky;
        bool vy = ((ty & 1) == 0) && ((unsigned)(ty >> 1) < 48u);
        int iy = vy ? (ty >> 1) : 0;
        for (int kx = 0; kx < 3; ++kx) {
            int tx = ox + 1 - kx;
            bool v = vy && ((tx & 1) == 0) && ((unsigned)(tx >> 1) < 48u);
            int ix = v ? (tx >> 1) : 0;
            const float* gp = gT + iy * 48 + ix;
            const float* wb = wt2 + (ky * 3 + kx) * 4096 + ocb;
            #pragma unroll 8
            for (int ic = 0; ic < 64; ++ic) {
                float gv = gp[ic * N_];
                gv = v ? gv : 0.f;
                const float* wr = wb + ic * 64;
                #pragma unroll
                for (int o = 0; o < 8; ++o) acc[o] += gv * wr[o];
            }
        }
    }
    const float* tb = ws + OFF_TBF;
    size_t base = ((size_t)(b * 64 + ocb) * 96 + oy) * 96 + ox;
    if (f32) {
        float* op = (float*)outp;
        #pragma unroll
        for (int o = 0; o < 8; ++o) op[base + (size_t)o * 9216] = acc[o] + tb[ocb + o];
    } else {
        bf16* op = (bf16*)outp;
        #pragma unroll
        for (int o = 0; o < 8; ++o)
            op[base + (size_t)o * 9216] = __float2bfloat16(acc[o] + tb[ocb + o]);
    }
}

// ---------------------------------------------------------------------------
extern "C" void kernel_launch(void* const* d_in, const int* in_sizes, int n_in,
                              void* d_out, int out_size, void* d_ws, size_t ws_size,
                              hipStream_t stream)
{
    float* ws = (float*)d_ws;

    hipLaunchKernelGGL(kc_prep, dim3(4608), dim3(256), 0, stream,
                       d_in[0], d_in[1], d_in[2], d_in[3], d_in[4], d_in[5],
                       d_in[6], d_in[7], d_in[8], d_in[9], d_in[10], ws);
    hipLaunchKernelGGL(k1_conv, dim3(9, 8, 2), dim3(256), 0, stream, ws);
    hipLaunchKernelGGL(tr_nc, dim3(288), dim3(256), 0, stream, ws);
    hipLaunchKernelGGL(k2_knn, dim3(288, 2), dim3(256), 0, stream, ws);
    hipLaunchKernelGGL(k2_merge, dim3(18), dim3(256), 0, stream, ws);
    hipLaunchKernelGGL(k_lin, dim3(18, 8, 2), dim3(256), 0, stream, ws);
    hipLaunchKernelGGL(k_attn12, dim3(18, 8, 2), dim3(256), 0, stream, ws);
    hipLaunchKernelGGL(k_lin2, dim3(18, 8), dim3(256), 0, stream, ws);
    hipLaunchKernelGGL(k_attn_out, dim3(18, 8), dim3(256), 0, stream, ws);
    hipLaunchKernelGGL(k7_tconv, dim3(36, 8, 2), dim3(256), 0, stream, ws,
                       d_in[1], d_out);
}

// Round 7
// 377.311 us; speedup vs baseline: 1.9586x; 1.2411x over previous
//
#include <hip/hip_runtime.h>
#include <hip/hip_bf16.h>
#include <stdint.h>

using bf16 = __hip_bfloat16;
using u64 = unsigned long long;

constexpr int B_ = 2;
constexpr int N_ = 2304;   // 48*48 post-conv nodes

// Workspace layout (float offsets). Max = 1,339,456 floats = 5.36 MB.
constexpr int OFF_WC2   = 0;        // conv w  [tap][ic][oc] (9*64*64)
constexpr int OFF_WT2   = 36864;    // tconv w [tap][ic][oc]
constexpr int OFF_W1F   = 73728;    // [64][64]
constexpr int OFF_W2F   = 77824;
constexpr int OFF_WOUTF = 81920;    // [128][64]
constexpr int OFF_A1F   = 90112;    // 128
constexpr int OFF_A2F   = 90240;
constexpr int OFF_AOUTF = 90368;
constexpr int OFF_CBF   = 90496;    // 64
constexpr int OFF_TBF   = 90560;    // 64
constexpr int OFF_FLAG  = 90624;    // 1: fp32 inputs; 0: bf16
constexpr int OFF_SQ    = 90688;    // [B*N]; SQ + six s-arrays contiguous (zeroed by kc)
constexpr int OFF_S11   = 95296;
constexpr int OFF_S12   = 99904;
constexpr int OFF_S21   = 104512;
constexpr int OFF_S22   = 109120;
constexpr int OFF_S1O   = 113728;
constexpr int OFF_S2O   = 118336;
constexpr int OFF_KNN   = 122944;   // int [B*N][8] (7 used)
constexpr int OFF_BUF0  = 159808;   // 294912 floats each
constexpr int OFF_BUF1  = 454720;
constexpr int OFF_BUF2  = 749632;
constexpr int OFF_BUF3  = 1044544;
// Lifetimes (no overlaps; x is read directly, never staged):
//  BUF0: featT   (k1 -> k_lin)      -> h2       (attn12 -> lin2)
//  BUF1: Wh1_nc  (k_lin -> attn12)  -> Whout_nc (lin2 -> attn_out)
//  BUF2: feat_nc (k1 -> k2)         -> h1       (attn12 -> lin2)
//  BUF3: PK      (k2 -> k2_merge)   -> Wh2_nc   (k_lin -> attn12) -> g (attn_out -> k7)
constexpr int OFF_PK    = OFF_BUF3;

__device__ __forceinline__ float bf2f_raw(unsigned short u) {
    return __uint_as_float(((unsigned int)u) << 16);
}

// order-preserving float -> u32 map
__device__ __forceinline__ unsigned int mono32(float f) {
    unsigned int u = __float_as_uint(f);
    return (u & 0x80000000u) ? ~u : (u | 0x80000000u);
}

// Dtype probe: 64 low-halves of conv_w; fp32 misread -> huge bf16 values.
__device__ __forceinline__ bool detect_f32(const void* conv_w) {
    const unsigned short* cw = (const unsigned short*)conv_w;
    float m = 0.f;
    #pragma unroll
    for (int u = 0; u < 64; ++u) {
        float v = fabsf(bf2f_raw(cw[u]));
        if (v < 3.0e38f) m = fmaxf(m, v);
    }
    return m > 1.0e4f;
}

// ---------------------------------------------------------------------------
// KC: weight convert/transpose + zero s-arrays + write dtype flag.
// grid 144 x 256.
// ---------------------------------------------------------------------------
__global__ __launch_bounds__(256) void kc_prep(
    const void* conv_w, const void* conv_b, const void* W1, const void* a1,
    const void* W2, const void* a2, const void* Wout, const void* aout,
    const void* tconv_w, const void* tconv_b, float* __restrict__ ws)
{
    bool f32 = detect_f32(conv_w);
    int idx = blockIdx.x * 256 + threadIdx.x;   // < 36864
    if (idx == 0) ws[OFF_FLAG] = f32 ? 1.f : 0.f;
    if (idx < 32256) ws[OFF_SQ + idx] = 0.f;    // SQ..S2O zero-init

    {
        int tap = idx >> 12, ic = (idx >> 6) & 63, oc = idx & 63;
        if (f32) {
            ws[OFF_WC2 + idx] = ((const float*)conv_w)[(oc * 64 + ic) * 9 + tap];
            ws[OFF_WT2 + idx] = ((const float*)tconv_w)[(ic * 64 + oc) * 9 + tap];
        } else {
            ws[OFF_WC2 + idx] = bf2f_raw(((const unsigned short*)conv_w)[(oc * 64 + ic) * 9 + tap]);
            ws[OFF_WT2 + idx] = bf2f_raw(((const unsigned short*)tconv_w)[(ic * 64 + oc) * 9 + tap]);
        }
    }
    if (idx < 4096) {
        if (f32) {
            ws[OFF_W1F + idx] = ((const float*)W1)[idx];
            ws[OFF_W2F + idx] = ((const float*)W2)[idx];
        } else {
            ws[OFF_W1F + idx] = bf2f_raw(((const unsigned short*)W1)[idx]);
            ws[OFF_W2F + idx] = bf2f_raw(((const unsigned short*)W2)[idx]);
        }
    }
    if (idx < 8192)
        ws[OFF_WOUTF + idx] = f32 ? ((const float*)Wout)[idx]
                                  : bf2f_raw(((const unsigned short*)Wout)[idx]);
    if (idx < 128) {
        if (f32) {
            ws[OFF_A1F + idx]   = ((const float*)a1)[idx];
            ws[OFF_A2F + idx]   = ((const float*)a2)[idx];
            ws[OFF_AOUTF + idx] = ((const float*)aout)[idx];
        } else {
            ws[OFF_A1F + idx]   = bf2f_raw(((const unsigned short*)a1)[idx]);
            ws[OFF_A2F + idx]   = bf2f_raw(((const unsigned short*)a2)[idx]);
            ws[OFF_AOUTF + idx] = bf2f_raw(((const unsigned short*)aout)[idx]);
        }
    }
    if (idx < 64) {
        if (f32) {
            ws[OFF_CBF + idx] = ((const float*)conv_b)[idx];
            ws[OFF_TBF + idx] = ((const float*)tconv_b)[idx];
        } else {
            ws[OFF_CBF + idx] = bf2f_raw(((const unsigned short*)conv_b)[idx]);
            ws[OFF_TBF + idx] = bf2f_raw(((const unsigned short*)tconv_b)[idx]);
        }
    }
}

// ---------------------------------------------------------------------------
// K1: 3x3 stride-2 conv pad 1 + fused sq atomic.  Reads x DIRECTLY (dual
// dtype).  Writes featT (BUF0, channel-major) and feat_nc (BUF2, node-major).
// grid (18, 8 oc, B) x 128.
// ---------------------------------------------------------------------------
template <bool F32>
__device__ __forceinline__ void conv_body(const void* __restrict__ x,
                                          float* __restrict__ ws,
                                          int n, int ocb, int b)
{
    int oy = n / 48, ox = n - (n / 48) * 48;
    const float* wc2 = ws + OFF_WC2;
    size_t xb = (size_t)b * 64 * 9216;
    float acc[8] = {0, 0, 0, 0, 0, 0, 0, 0};

    for (int ky = 0; ky < 3; ++ky) {
        int iy = 2 * oy - 1 + ky;
        bool vy = (unsigned)iy < 96u;
        int iyc = vy ? iy : 0;
        for (int kx = 0; kx < 3; ++kx) {
            int ix = 2 * ox - 1 + kx;
            bool v = vy && ((unsigned)ix < 96u);
            int ixc = v ? ix : 0;
            size_t xoff = xb + iyc * 96 + ixc;
            const float* wb = wc2 + (ky * 3 + kx) * 4096 + ocb;
            #pragma unroll 8
            for (int ic = 0; ic < 64; ++ic) {
                float xv;
                if (F32) xv = ((const float*)x)[xoff + ic * 9216];
                else     xv = bf2f_raw(((const unsigned short*)x)[xoff + ic * 9216]);
                xv = v ? xv : 0.f;
                const float* wr = wb + ic * 64;
                #pragma unroll
                for (int o = 0; o < 8; ++o) acc[o] += xv * wr[o];
            }
        }
    }
    float* featT = ws + OFF_BUF0 + (size_t)b * 64 * N_;
    const float* cb = ws + OFF_CBF;
    float ssum = 0.f;
    #pragma unroll
    for (int o = 0; o < 8; ++o) {
        float f = acc[o] + cb[ocb + o];
        acc[o] = f;
        featT[(ocb + o) * N_ + n] = f;
        ssum += f * f;
    }
    float4* fnc = (float4*)(ws + OFF_BUF2 + ((size_t)(b * N_ + n) * 64 + ocb));
    fnc[0] = make_float4(acc[0], acc[1], acc[2], acc[3]);
    fnc[1] = make_float4(acc[4], acc[5], acc[6], acc[7]);
    atomicAdd(ws + OFF_SQ + b * N_ + n, ssum);
}

__global__ __launch_bounds__(128) void k1_conv(const void* __restrict__ x,
                                               float* __restrict__ ws)
{
    int n   = blockIdx.x * 128 + threadIdx.x;   // 0..2303
    int ocb = blockIdx.y * 8;
    int b   = blockIdx.z;
    if (ws[OFF_FLAG] != 0.f) conv_body<true >(x, ws, n, ocb, b);
    else                     conv_body<false>(x, ws, n, ocb, b);
}

// ---------------------------------------------------------------------------
// K2: top-7 per row over half the j-range.  Block = 4 waves = 16 rows (LDS),
// wave owns 4 rows; 2-j unroll amortizes fi LDS reads.  Keys u64
// (mono(y)<<32 | j): strict < == stable-argsort order; static indexing only
// (no scratch).  Sorted 7-list partials -> PK.  grid (288, 2) x 256.
// ---------------------------------------------------------------------------
__global__ __launch_bounds__(256) void k2_knn(float* __restrict__ ws)
{
    __shared__ float4 fi[16][16];     // [row][c4]
    int tid = threadIdx.x;
    int i0  = blockIdx.x * 16;
    int jh  = blockIdx.y;
    int b   = i0 / N_;
    const float4* fnc4 = (const float4*)(ws + OFF_BUF2);
    const float* sq  = ws + OFF_SQ + b * N_;

    {
        int r = tid >> 4, c4 = tid & 15;
        fi[r][c4] = fnc4[(size_t)(i0 + r) * 16 + c4];
    }
    __syncthreads();

    int w = tid >> 6, lane = tid & 63;
    int r0 = w * 4;

    u64 k[4][7];
    #pragma unroll
    for (int r = 0; r < 4; ++r)
        #pragma unroll
        for (int t = 0; t < 7; ++t) k[r][t] = ~0ull;

    int jbase = jh * 1152 + lane;
    for (int t = 0; t < 9; ++t) {
        int j0 = jbase + t * 128;
        int j1 = j0 + 64;
        const float4* fj0 = fnc4 + (size_t)(b * N_ + j0) * 16;
        const float4* fj1 = fnc4 + (size_t)(b * N_ + j1) * 16;
        float4 acc[2][4];
        #pragma unroll
        for (int q = 0; q < 2; ++q)
            #pragma unroll
            for (int r = 0; r < 4; ++r) acc[q][r] = make_float4(0.f, 0.f, 0.f, 0.f);
        #pragma unroll
        for (int c4 = 0; c4 < 16; ++c4) {
            float4 A = fj0[c4], Bv = fj1[c4];
            #pragma unroll
            for (int r = 0; r < 4; ++r) {
                float4 f = fi[r0 + r][c4];
                acc[0][r].x += A.x * f.x;  acc[0][r].y += A.y * f.y;
                acc[0][r].z += A.z * f.z;  acc[0][r].w += A.w * f.w;
                acc[1][r].x += Bv.x * f.x; acc[1][r].y += Bv.y * f.y;
                acc[1][r].z += Bv.z * f.z; acc[1][r].w += Bv.w * f.w;
            }
        }
        float sq0 = sq[j0], sq1 = sq[j1];
        #pragma unroll
        for (int q = 0; q < 2; ++q) {
            int j = q ? j1 : j0;
            float sqj = q ? sq1 : sq0;
            #pragma unroll
            for (int r = 0; r < 4; ++r) {
                float4 a = acc[q][r];
                float y = sqj - 2.f * ((a.x + a.y) + (a.z + a.w));
                u64 key = ((u64)mono32(y) << 32) | (unsigned int)j;
                if (key < k[r][6]) {
                    int pos = 0;
                    #pragma unroll
                    for (int s = 0; s < 7; ++s) pos += (k[r][s] < key) ? 1 : 0;
                    #pragma unroll
                    for (int p = 6; p > 0; --p)
                        k[r][p] = (p == pos) ? key : ((p > pos) ? k[r][p - 1] : k[r][p]);
                    if (pos == 0) k[r][0] = key;
                }
            }
        }
    }

    // 7-pass wave merge per row; consume-by-equality (static indices only)
    u64* pk = (u64*)(ws + OFF_PK);
    #pragma unroll
    for (int r = 0; r < 4; ++r) {
        u64 myk = 0;
        for (int pass = 0; pass < 7; ++pass) {
            u64 m = k[r][0];
            #pragma unroll
            for (int s = 1; s < 7; ++s) m = (k[r][s] < m) ? k[r][s] : m;
            #pragma unroll
            for (int off = 1; off < 64; off <<= 1) {
                u64 o = (u64)__shfl_xor((long long)m, off);
                m = (o < m) ? o : m;
            }
            #pragma unroll
            for (int s = 0; s < 7; ++s)
                if (k[r][s] == m) k[r][s] = ~0ull;
            if (lane == pass) myk = m;
        }
        if (lane < 7)
            pk[((size_t)(i0 + r0 + r) * 2 + jh) * 8 + lane] = myk;
    }
}

// ---------------------------------------------------------------------------
// K2M: rank-merge the two sorted 7-lists per row -> KNN.  grid 18 x 256.
// ---------------------------------------------------------------------------
__global__ __launch_bounds__(256) void k2_merge(float* __restrict__ ws)
{
    int row = blockIdx.x * 256 + threadIdx.x;   // < 4608
    const u64* pk = (const u64*)(ws + OFF_PK) + (size_t)row * 16;
    int* kout = (int*)(ws + OFF_KNN) + (size_t)row * 8;
    u64 A[7], Bk[7];
    #pragma unroll
    for (int q = 0; q < 7; ++q) { A[q] = pk[q]; Bk[q] = pk[8 + q]; }
    #pragma unroll
    for (int q = 0; q < 7; ++q) {
        int rank = q;
        #pragma unroll
        for (int p = 0; p < 7; ++p) rank += (Bk[p] < A[q]) ? 1 : 0;
        if (rank < 7) kout[rank] = (int)(A[q] & 0xffffffffull);
    }
    #pragma unroll
    for (int q = 0; q < 7; ++q) {
        int rank = q;
        #pragma unroll
        for (int p = 0; p < 7; ++p) rank += (A[p] < Bk[q]) ? 1 : 0;
        if (rank < 7) kout[rank] = (int)(Bk[q] & 0xffffffffull);
    }
}

// ---------------------------------------------------------------------------
// K_lin: both GAT input projections; node-major Wh_nc out + s1/s2 atomics.
// grid (18, 8 oc, 2 layers) x 256.
// ---------------------------------------------------------------------------
__global__ __launch_bounds__(256) void k_lin(float* __restrict__ ws)
{
    int layer = blockIdx.z;
    const float* W  = ws + (layer ? OFF_W2F : OFF_W1F);
    const float* a  = ws + (layer ? OFF_A2F : OFF_A1F);
    float* out_nc   = ws + (layer ? OFF_BUF3 : OFF_BUF1);
    float* s1       = ws + (layer ? OFF_S21 : OFF_S11);
    float* s2       = ws + (layer ? OFF_S22 : OFF_S12);
    int ocb = blockIdx.y * 8;
    int i = blockIdx.x * 256 + threadIdx.x;
    int b = i / N_, n = i - b * N_;
    const float* in_b = ws + OFF_BUF0 + (size_t)b * 64 * N_;

    float acc[8] = {0, 0, 0, 0, 0, 0, 0, 0};
    #pragma unroll 8
    for (int kk = 0; kk < 64; ++kk) {
        float xv = in_b[kk * N_ + n];
        const float* wr = W + kk * 64 + ocb;
        #pragma unroll
        for (int o = 0; o < 8; ++o) acc[o] += xv * wr[o];
    }
    float4* ob = (float4*)(out_nc + ((size_t)i * 64 + ocb));
    ob[0] = make_float4(acc[0], acc[1], acc[2], acc[3]);
    ob[1] = make_float4(acc[4], acc[5], acc[6], acc[7]);
    float p1 = 0.f, p2 = 0.f;
    #pragma unroll
    for (int o = 0; o < 8; ++o) {
        p1 += acc[o] * a[ocb + o];
        p2 += acc[o] * a[64 + ocb + o];
    }
    atomicAdd(s1 + i, p1);
    atomicAdd(s2 + i, p2);
}

// ---------------------------------------------------------------------------
// K_lin2: Whout_nc = [h1|h2] @ Wout.  h1=BUF2, h2=BUF0 (channel-major),
// out=BUF1 node-major.  grid (18, 8) x 256.
// ---------------------------------------------------------------------------
__global__ __launch_bounds__(256) void k_lin2(float* __restrict__ ws)
{
    int ocb = blockIdx.y * 8;
    int i = blockIdx.x * 256 + threadIdx.x;
    int b = i / N_, n = i - b * N_;
    const float* h1 = ws + OFF_BUF2 + (size_t)b * 64 * N_;
    const float* h2 = ws + OFF_BUF0 + (size_t)b * 64 * N_;
    const float* W  = ws + OFF_WOUTF;
    const float* a  = ws + OFF_AOUTF;

    float acc[8] = {0, 0, 0, 0, 0, 0, 0, 0};
    #pragma unroll 8
    for (int kk = 0; kk < 64; ++kk) {
        float xv = h1[kk * N_ + n];
        const float* wr = W + kk * 64 + ocb;
        #pragma unroll
        for (int o = 0; o < 8; ++o) acc[o] += xv * wr[o];
    }
    #pragma unroll 8
    for (int kk = 0; kk < 64; ++kk) {
        float xv = h2[kk * N_ + n];
        const float* wr = W + (64 + kk) * 64 + ocb;
        #pragma unroll
        for (int o = 0; o < 8; ++o) acc[o] += xv * wr[o];
    }
    float4* ob = (float4*)(ws + OFF_BUF1 + ((size_t)i * 64 + ocb));
    ob[0] = make_float4(acc[0], acc[1], acc[2], acc[3]);
    ob[1] = make_float4(acc[4], acc[5], acc[6], acc[7]);
    float p1 = 0.f, p2 = 0.f;
    #pragma unroll
    for (int o = 0; o < 8; ++o) {
        p1 += acc[o] * a[ocb + o];
        p2 += acc[o] * a[64 + ocb + o];
    }
    atomicAdd(ws + OFF_S1O + i, p1);
    atomicAdd(ws + OFF_S2O + i, p2);
}

// ---------------------------------------------------------------------------
// attention body: softmax over 7-NN (node-major float4 gathers) + ELU,
// writes 16 channels (ccb..ccb+15) channel-major.
// ---------------------------------------------------------------------------
__device__ __forceinline__ void attn_body(
    const float* __restrict__ Wh_nc, const float* __restrict__ s1,
    const float* __restrict__ s2, const int* __restrict__ knn,
    float* __restrict__ out, int i, int b, int n, int ccb)
{
    const int* kp = knn + (size_t)i * 8;
    int j[7];
    #pragma unroll
    for (int t = 0; t < 7; ++t) {
        int jt = kp[t];
        j[t] = ((unsigned)jt < (unsigned)N_) ? jt : 0;
    }
    float si = s1[i];
    const float* s2b = s2 + b * N_;
    float e[7];
    #pragma unroll
    for (int t = 0; t < 7; ++t) {
        float v = si + s2b[j[t]];
        e[t] = v > 0.f ? v : 0.2f * v;     // leaky_relu 0.2
    }
    float m = e[0];
    #pragma unroll
    for (int t = 1; t < 7; ++t) m = fmaxf(m, e[t]);
    float ssum = 0.f;
    #pragma unroll
    for (int t = 0; t < 7; ++t) { e[t] = __expf(e[t] - m); ssum += e[t]; }
    float inv = 1.f / ssum;
    #pragma unroll
    for (int t = 0; t < 7; ++t) e[t] *= inv;

    const float4* W4 = (const float4*)Wh_nc;
    float* ob = out + (size_t)b * 64 * N_;
    #pragma unroll
    for (int c4 = ccb / 4; c4 < ccb / 4 + 4; ++c4) {
        float4 acc = make_float4(0.f, 0.f, 0.f, 0.f);
        #pragma unroll
        for (int t = 0; t < 7; ++t) {
            float4 v = W4[(size_t)(b * N_ + j[t]) * 16 + c4];
            acc.x += e[t] * v.x; acc.y += e[t] * v.y;
            acc.z += e[t] * v.z; acc.w += e[t] * v.w;
        }
        acc.x = acc.x > 0.f ? acc.x : expm1f(acc.x);
        acc.y = acc.y > 0.f ? acc.y : expm1f(acc.y);
        acc.z = acc.z > 0.f ? acc.z : expm1f(acc.z);
        acc.w = acc.w > 0.f ? acc.w : expm1f(acc.w);
        ob[(c4 * 4 + 0) * N_ + n] = acc.x;
        ob[(c4 * 4 + 1) * N_ + n] = acc.y;
        ob[(c4 * 4 + 2) * N_ + n] = acc.z;
        ob[(c4 * 4 + 3) * N_ + n] = acc.w;
    }
}

// grid (18, 4 c-groups, 2 layers) x 256
__global__ __launch_bounds__(256) void k_attn12(float* __restrict__ ws)
{
    int layer = blockIdx.z;
    const float* Wh_nc = ws + (layer ? OFF_BUF3 : OFF_BUF1);
    const float* s1    = ws + (layer ? OFF_S21 : OFF_S11);
    const float* s2    = ws + (layer ? OFF_S22 : OFF_S12);
    float* out         = ws + (layer ? OFF_BUF0 : OFF_BUF2);
    int ccb = blockIdx.y * 16;
    int i = blockIdx.x * 256 + threadIdx.x;
    int b = i / N_, n = i - b * N_;
    attn_body(Wh_nc, s1, s2, (const int*)(ws + OFF_KNN), out, i, b, n, ccb);
}

// grid (18, 4) x 256
__global__ __launch_bounds__(256) void k_attn_out(float* __restrict__ ws)
{
    int ccb = blockIdx.y * 16;
    int i = blockIdx.x * 256 + threadIdx.x;
    int b = i / N_, n = i - b * N_;
    attn_body(ws + OFF_BUF1, ws + OFF_S1O, ws + OFF_S2O,
              (const int*)(ws + OFF_KNN), ws + OFF_BUF3, i, b, n, ccb);
}

// ---------------------------------------------------------------------------
// K7: ConvTranspose2d k=3 s=2 p=1 op=1 : 48x48 -> 96x96, reads g=BUF3.
// grid (36, 8 oc, B) x 256; dual-dtype output store via ws flag.
// ---------------------------------------------------------------------------
__global__ __launch_bounds__(256) void k7_tconv(float* __restrict__ ws,
                                                void* __restrict__ outp)
{
    bool f32 = ws[OFF_FLAG] != 0.f;
    int pix = blockIdx.x * 256 + threadIdx.x;   // 0..9215
    int ocb = blockIdx.y * 8;
    int b   = blockIdx.z;
    int oy = pix / 96, ox = pix - (pix / 96) * 96;

    const float* gT  = ws + OFF_BUF3 + (size_t)b * 64 * N_;
    const float* wt2 = ws + OFF_WT2;
    float acc[8] = {0, 0, 0, 0, 0, 0, 0, 0};

    for (int ky = 0; ky < 3; ++ky) {
        int ty = oy + 1 - ky;
        bool vy = ((ty & 1) == 0) && ((unsigned)(ty >> 1) < 48u);
        int iy = vy ? (ty >> 1) : 0;
        for (int kx = 0; kx < 3; ++kx) {
            int tx = ox + 1 - kx;
            bool v = vy && ((tx & 1) == 0) && ((unsigned)(tx >> 1) < 48u);
            int ix = v ? (tx >> 1) : 0;
            const float* gp = gT + iy * 48 + ix;
            const float* wb = wt2 + (ky * 3 + kx) * 4096 + ocb;
            #pragma unroll 8
            for (int ic = 0; ic < 64; ++ic) {
                float gv = gp[ic * N_];
                gv = v ? gv : 0.f;
                const float* wr = wb + ic * 64;
                #pragma unroll
                for (int o = 0; o < 8; ++o) acc[o] += gv * wr[o];
            }
        }
    }
    const float* tb = ws + OFF_TBF;
    size_t base = ((size_t)(b * 64 + ocb) * 96 + oy) * 96 + ox;
    if (f32) {
        float* op = (float*)outp;
        #pragma unroll
        for (int o = 0; o < 8; ++o) op[base + (size_t)o * 9216] = acc[o] + tb[ocb + o];
    } else {
        bf16* op = (bf16*)outp;
        #pragma unroll
        for (int o = 0; o < 8; ++o)
            op[base + (size_t)o * 9216] = __float2bfloat16(acc[o] + tb[ocb + o]);
    }
}

// ---------------------------------------------------------------------------
extern "C" void kernel_launch(void* const* d_in, const int* in_sizes, int n_in,
                              void* d_out, int out_size, void* d_ws, size_t ws_size,
                              hipStream_t stream)
{
    float* ws = (float*)d_ws;

    hipLaunchKernelGGL(kc_prep, dim3(144), dim3(256), 0, stream,
                       d_in[1], d_in[2], d_in[3], d_in[4], d_in[5], d_in[6],
                       d_in[7], d_in[8], d_in[9], d_in[10], ws);
    hipLaunchKernelGGL(k1_conv, dim3(18, 8, 2), dim3(128), 0, stream, d_in[0], ws);
    hipLaunchKernelGGL(k2_knn, dim3(288, 2), dim3(256), 0, stream, ws);
    hipLaunchKernelGGL(k2_merge, dim3(18), dim3(256), 0, stream, ws);
    hipLaunchKernelGGL(k_lin, dim3(18, 8, 2), dim3(256), 0, stream, ws);
    hipLaunchKernelGGL(k_attn12, dim3(18, 4, 2), dim3(256), 0, stream, ws);
    hipLaunchKernelGGL(k_lin2, dim3(18, 8), dim3(256), 0, stream, ws);
    hipLaunchKernelGGL(k_attn_out, dim3(18, 4), dim3(256), 0, stream, ws);
    hipLaunchKernelGGL(k7_tconv, dim3(36, 8, 2), dim3(256), 0, stream, ws, d_out);
}